// Round 12
// baseline (213.033 us; speedup 1.0000x reference)
//
#include <hip/hip_runtime.h>

#define N_NODES 100000
#define N_EDGES 600000
#define K_DIM 128
#define M2 64
#define NT_TILES ((N_NODES + 63) / 64)        // 1563 64-node tiles
#define GEMM_GRID 256

// single-pass bucket build (v11)
#define NBKT 800                              // buckets
#define NPB 125                               // nodes per bucket (800*125 = 100000)
#define HIST_BLOCKS 64
#define EPB (N_EDGES / HIST_BLOCKS)           // 9375 edges per hist block (exact)
#define BSTRIDE 1024                          // fixed per-bucket capacity; Binomial max ~890 (>10 sigma)

using frag_ab = __attribute__((ext_vector_type(8))) short;   // 8 bf16 = 4 VGPRs
using frag_cd = __attribute__((ext_vector_type(4))) float;   // 4 fp32 acc

// fp32 -> bf16 round-to-nearest-even
__device__ __forceinline__ unsigned short f2b(float f) {
  unsigned u = __builtin_bit_cast(unsigned, f);
  u = (u + 0x7fffu + ((u >> 16) & 1u)) >> 16;
  return (unsigned short)u;
}

// async global->LDS, 16 B per lane. LDS dest wave-uniform (HW adds lane*16);
// global src per-lane (swizzled LDS layouts = pre-swizzle the source).
__device__ __forceinline__ void gload_lds16(const void* gsrc, void* ldst) {
  __builtin_amdgcn_global_load_lds(
      (const __attribute__((address_space(1))) void*)gsrc,
      (__attribute__((address_space(3))) void*)ldst, 16, 0, 0);
}

// raw barrier: drain LDS ops only, keep DMA/stores (vmcnt) in flight
__device__ __forceinline__ void lgkm_barrier() {
  __builtin_amdgcn_sched_barrier(0);
  asm volatile("s_waitcnt lgkmcnt(0)" ::: "memory");
  __builtin_amdgcn_s_barrier();
  __builtin_amdgcn_sched_barrier(0);
}

// ---------------- fused: single-pass bucket build + x->bf16 + weight transposes ----------------
// v11: hist blocks do hist -> global reserve -> SCATTER in one kernel. Fixed-stride buckets
// (b*1024) make the bucket-offset scan unnecessary; re-running the LDS atomicAdd in the
// scatter pass re-assigns unique slots, so the pos[] round-trip is gone. scan_buckets and
// bucket_scatter kernels are deleted (6 launches -> 4).
// NOTE (v8 post-mortem): do NOT replace node-parallel gather with edge-parallel LDS-f32-atomic
// accumulation — stride-8 lane layout = 16-way ds_add bank conflict = 503us. Clamped duplicate
// gather loads are same-address cache hits, NOT wasted HBM traffic.
#define XB_BLOCKS ((N_NODES * K_DIM / 4 + 255) / 256)            // 12500
#define W_ELEMS ((128 + 128 + 64 + 64) * 128)                    // 49152
#define WB_BLOCKS ((W_ELEMS + 255) / 256)                        // 192
__global__ __launch_bounds__(256) void conv_all(const float* __restrict__ x,
                                                unsigned short* __restrict__ xb,
                                                const float* __restrict__ Ws1,
                                                const float* __restrict__ Wn1,
                                                const float* __restrict__ Ws2,
                                                const float* __restrict__ Wn2,
                                                unsigned short* __restrict__ Ws1T,
                                                unsigned short* __restrict__ Wn1T,
                                                unsigned short* __restrict__ Ws2T,
                                                unsigned short* __restrict__ Wn2T,
                                                const int* __restrict__ src,
                                                const int* __restrict__ dst,
                                                int* __restrict__ gbucket,
                                                int* __restrict__ ebuf) {
  __shared__ int lcnt[NBKT];
  __shared__ int lbase[NBKT];
  if (blockIdx.x < HIST_BLOCKS) {
    int tid = threadIdx.x;
    for (int i = tid; i < NBKT; i += 256) lcnt[i] = 0;
    __syncthreads();
    int e0 = blockIdx.x * EPB;
    // pass 1: local histogram
    for (int e = e0 + tid; e < e0 + EPB; e += 256)
      atomicAdd(&lcnt[dst[e] / NPB], 1);
    __syncthreads();
    // reserve global ranges, reset local counters
    for (int i = tid; i < NBKT; i += 256) {
      int c = lcnt[i];
      lbase[i] = c ? atomicAdd(&gbucket[i], c) : 0;
      lcnt[i] = 0;
    }
    __syncthreads();
    // pass 2: scatter (dst/src re-reads are L2-hot; fresh LDS-atomic slots are unique)
    for (int e = e0 + tid; e < e0 + EPB; e += 256) {
      int d = dst[e];
      int b = d / NPB;
      int p = lbase[b] + atomicAdd(&lcnt[b], 1);
      ebuf[b * BSTRIDE + p] = src[e] | ((d - b * NPB) << 20);
    }
  } else if (blockIdx.x < HIST_BLOCKS + XB_BLOCKS) {
    long i = (long)(blockIdx.x - HIST_BLOCKS) * 256 + threadIdx.x;
    if (i >= (long)N_NODES * K_DIM / 4) return;
    float4 v = *(const float4*)(x + i * 4);
    ushort4 o;
    o.x = f2b(v.x); o.y = f2b(v.y); o.z = f2b(v.z); o.w = f2b(v.w);
    *(ushort4*)(xb + i * 4) = o;
  } else {
    int i = (blockIdx.x - HIST_BLOCKS - XB_BLOCKS) * 256 + threadIdx.x;
    if (i >= W_ELEMS) return;
    const float* W;
    unsigned short* WT;
    int M, li;
    if (i < 128 * 128)               { W = Ws1; WT = Ws1T; M = 128; li = i; }
    else if (i < 2 * 128 * 128)      { W = Wn1; WT = Wn1T; M = 128; li = i - 128 * 128; }
    else if (i < 2 * 128 * 128 + 64 * 128) { W = Ws2; WT = Ws2T; M = 64; li = i - 2 * 128 * 128; }
    else                             { W = Wn2; WT = Wn2T; M = 64; li = i - 2 * 128 * 128 - 64 * 128; }
    int n = li >> 7, k = li & 127;   // li = n*128 + k
    WT[li] = f2b(W[k * M + n]);
  }
}

// ---------------- fused per-bucket CSR sort + layer-1 gather-mean (v10, v11-indexed) ----------------
// bs = b*BSTRIDE (fixed stride; no scan). Emits padded rp[b*126+i] (126 entries/bucket, last =
// bucket total) + csr_src (padded layout) for aggregate64_add. Gather stays NODE-parallel with
// register accumulators (v8 lesson: no LDS-f32 atomics).
__global__ __launch_bounds__(512) void bucket_csr_agg1(const unsigned short* __restrict__ xb,
                                                       const int* __restrict__ ebuf,
                                                       const int* __restrict__ gbucket,
                                                       int* __restrict__ rp,
                                                       int* __restrict__ csr_src,
                                                       unsigned short* __restrict__ aggb) {
  __shared__ int cnt[128];
  __shared__ int sedge[BSTRIDE];   // node-sorted src ids, 4 KB
  int tid = threadIdx.x, b = blockIdx.x;
  int bs = b * BSTRIDE;
  int ecnt = gbucket[b];
  for (int i = tid; i < 128; i += 512) cnt[i] = 0;
  __syncthreads();

  int ln[2], lp[2], sv[2];
#pragma unroll
  for (int j = 0; j < 2; ++j) {            // capacity 2*512 = 1024 = BSTRIDE
    int p = tid + j * 512;
    if (p < ecnt) {
      int pk = ebuf[bs + p];
      sv[j] = pk & 0xFFFFF;
      ln[j] = pk >> 20;
      lp[j] = atomicAdd(&cnt[ln[j]], 1);
    }
  }
  __syncthreads();
  // inclusive scan over cnt[0..127]
  for (int off = 1; off < 128; off <<= 1) {
    int t = 0;
    if (tid < 128 && tid >= off) t = cnt[tid - off];
    __syncthreads();
    if (tid < 128) cnt[tid] += t;
    __syncthreads();
  }
  for (int i = tid; i < 126; i += 512)
    rp[b * 126 + i] = bs + (i ? cnt[i - 1] : 0);   // i=125 -> cnt[124] = bucket total
#pragma unroll
  for (int j = 0; j < 2; ++j) {
    int p = tid + j * 512;
    if (p < ecnt) {
      int l = ln[j];
      int loc = (l ? cnt[l - 1] : 0) + lp[j];
      sedge[loc] = sv[j];
      csr_src[bs + loc] = sv[j];   // for aggregate64_add
    }
  }
  __syncthreads();

  // gather-mean from LDS edge list: 16 threads/node, 32 nodes per pass
  int nl = tid >> 4;
  int c = (tid & 15) << 3;   // 8 bf16 per thread
  for (int n0 = 0; n0 < NPB; n0 += 32) {
    int node = n0 + nl;
    if (node < NPB) {
      int beg = node ? cnt[node - 1] : 0;
      int end = cnt[node];
      float acc[8];
#pragma unroll
      for (int j = 0; j < 8; ++j) acc[j] = 0.f;
      for (int e0 = beg; e0 < end; e0 += 8) {
        int idx[8];
#pragma unroll
        for (int p = 0; p < 8; ++p) idx[p] = sedge[min(e0 + p, end - 1)];
        uint4 v[8];
#pragma unroll
        for (int p = 0; p < 8; ++p) v[p] = *(const uint4*)(xb + (size_t)idx[p] * K_DIM + c);
#pragma unroll
        for (int p = 0; p < 8; ++p) {
          float m = (e0 + p < end) ? 1.f : 0.f;
          unsigned u[4] = {v[p].x, v[p].y, v[p].z, v[p].w};
#pragma unroll
          for (int j = 0; j < 4; ++j) {
            acc[2 * j]     += m * __builtin_bit_cast(float, u[j] << 16);
            acc[2 * j + 1] += m * __builtin_bit_cast(float, u[j] & 0xffff0000u);
          }
        }
      }
      float inv = 1.0f / (float)max(end - beg, 1);
      uint4 o;
      unsigned* op = (unsigned*)&o;
#pragma unroll
      for (int j = 0; j < 4; ++j) {
        unsigned lo = f2b(acc[2 * j] * inv);
        unsigned hi = f2b(acc[2 * j + 1] * inv);
        op[j] = lo | (hi << 16);
      }
      *(uint4*)(aggb + (size_t)(b * NPB + node) * K_DIM + c) = o;
    }
  }
}

// ---------------- gather-mean-add, 64 bf16 cols -> out fp32 (v11: padded rp indexing) ----------------
__global__ __launch_bounds__(256) void aggregate64_add(const unsigned short* __restrict__ g,
                                                       const int* __restrict__ rp,
                                                       const int* __restrict__ csr_src,
                                                       float* __restrict__ out, int n) {
  int t = blockIdx.x * blockDim.x + threadIdx.x;
  int node = t >> 3;
  int c = (t & 7) << 3;  // 8 bf16 per thread
  if (node >= n) return;
  int b = node / NPB;
  int i = node - b * NPB;
  int beg = rp[b * 126 + i], end = rp[b * 126 + i + 1];
  float acc[8];
#pragma unroll
  for (int j = 0; j < 8; ++j) acc[j] = 0.f;

  if (end > beg) {
    for (int e0 = beg; e0 < end; e0 += 8) {
      int idx[8];
#pragma unroll
      for (int p = 0; p < 8; ++p) idx[p] = csr_src[min(e0 + p, end - 1)];
      uint4 v[8];
#pragma unroll
      for (int p = 0; p < 8; ++p) v[p] = *(const uint4*)(g + (size_t)idx[p] * M2 + c);
#pragma unroll
      for (int p = 0; p < 8; ++p) {
        float m = (e0 + p < end) ? 1.f : 0.f;
        unsigned u[4] = {v[p].x, v[p].y, v[p].z, v[p].w};
#pragma unroll
        for (int j = 0; j < 4; ++j) {
          acc[2 * j]     += m * __builtin_bit_cast(float, u[j] << 16);
          acc[2 * j + 1] += m * __builtin_bit_cast(float, u[j] & 0xffff0000u);
        }
      }
    }
  }
  float inv = 1.0f / (float)max(end - beg, 1);
  float* op = out + (size_t)node * M2 + c;
  float4 o0 = *(float4*)(op);
  float4 o1 = *(float4*)(op + 4);
  o0.x += acc[0] * inv; o0.y += acc[1] * inv; o0.z += acc[2] * inv; o0.w += acc[3] * inv;
  o1.x += acc[4] * inv; o1.y += acc[5] * inv; o1.z += acc[6] * inv; o1.w += acc[7] * inv;
  *(float4*)(op) = o0;
  *(float4*)(op + 4) = o1;
}

// stage one 64-node tile of x+agg (32 KB) into LDS dbuf half, swizzled source
__device__ __forceinline__ void stage_tile(const unsigned short* xb, const unsigned short* aggb,
                                           int t, char* dstbase, int tid, int wave, int N) {
#pragma unroll
  for (int it = 0; it < 2; ++it) {
    int L = it * 8192 + tid * 16;            // [0, 16384)
    int row = L >> 8;                        // 0..63
    int srb = (L & 255) ^ ((row & 7) << 4);  // inverse-swizzled source byte
    int node = t * 64 + row;
    if (node >= N) node = N - 1;             // clamp (garbage rows never stored)
    char* d = dstbase + it * 8192 + wave * 1024;  // wave-uniform; HW adds lane*16
    gload_lds16((const char*)xb + (size_t)node * 256 + srb, d);
    gload_lds16((const char*)aggb + (size_t)node * 256 + srb, d + 16384);
  }
}

// ---------------- fused both-layer GEMM (v5: persistent, everything via DMA+LDS) ----------------
// Confirmed working (rounds 6-11). Rule from v1-v4: any global->VGPR operand load feeding
// MFMA gets latency-serialized by the compiler; global_load_lds is the only reliably-batched
// path. Persistent blocks (grid=256, 1/CU, 512 thr), weights staged ONCE, x/agg 2x32K dbuf
// with one-tile-ahead DMA; raw lgkm-only barriers keep the prefetch DMA in flight.
__global__ __launch_bounds__(512, 2) void sage_fused_gemm(const unsigned short* __restrict__ xb,
                                                          const unsigned short* __restrict__ aggb,
                                                          const unsigned short* __restrict__ Ws1T,
                                                          const unsigned short* __restrict__ Wn1T,
                                                          const float* __restrict__ b1,
                                                          const unsigned short* __restrict__ Ws2T,
                                                          const unsigned short* __restrict__ Wn2T,
                                                          const float* __restrict__ b2,
                                                          float* __restrict__ out,
                                                          unsigned short* __restrict__ g, int N) {
  // [0,32K) Ws1T | [32K,64K) Wn1T | [64K,80K) Ws2T | [80K,96K) Wn2T | [96K,128K) buf0 | [128K,160K) buf1
  __shared__ char sL[163840];

  const int tid = threadIdx.x;
  const int wave = tid >> 6;
  const int lane = tid & 63;
  const int l15 = lane & 15;
  const int q = lane >> 4;
  const int nodeq = wave >> 1;     // 0..3 -> 16-node strip
  const int fhalf = wave & 1;      // phase-1 feat half / phase-2 output matrix
  const int fbase = fhalf * 64;

  // ---- prologue: stage all weights (96 KB) + first tile (once per block) ----
#pragma unroll
  for (int it = 0; it < 4; ++it) {           // W1: 2 x 32K
    int L = it * 8192 + tid * 16;
    int row = L >> 8;
    int srb = (L & 255) ^ ((row & 7) << 4);
    char* d = sL + it * 8192 + wave * 1024;
    gload_lds16((const char*)Ws1T + row * 256 + srb, d);
    gload_lds16((const char*)Wn1T + row * 256 + srb, d + 32768);
  }
#pragma unroll
  for (int it = 0; it < 2; ++it) {           // W2: 2 x 16K
    int L = it * 8192 + tid * 16;
    int row = L >> 8;
    int srb = (L & 255) ^ ((row & 7) << 4);
    char* d = sL + 65536 + it * 8192 + wave * 1024;
    gload_lds16((const char*)Ws2T + row * 256 + srb, d);
    gload_lds16((const char*)Wn2T + row * 256 + srb, d + 16384);
  }
  int tt = blockIdx.x;
  if (tt < NT_TILES) stage_tile(xb, aggb, tt, sL + 98304, tid, wave, N);

  // ---- biases: loop-invariant plain loads (hoisted; once per block) ----
  float4 bv1[4], bv2[4];
#pragma unroll
  for (int ft = 0; ft < 4; ++ft) {
    bv1[ft] = *(const float4*)(b1 + fbase + ft * 16 + q * 4);
    bv2[ft] = *(const float4*)(b2 + ft * 16 + q * 4);
  }

  // ---- persistent tile loop ----
  int li = 0;
  for (; tt < NT_TILES; tt += GEMM_GRID, ++li) {
    char* cur = sL + 98304 + (li & 1) * 32768;
    char* nxt = sL + 98304 + ((li + 1) & 1) * 32768;

    __syncthreads();  // B1: vmcnt(0) drain -> DMA(cur) complete; prev phase-2 LDS reads done

    if (tt + GEMM_GRID < NT_TILES)           // prefetch next tile (stays in flight across
      stage_tile(xb, aggb, tt + GEMM_GRID, nxt, tid, wave, N);  // the raw barriers below)

    // ---- phase 1: h1 = relu(x@Ws1 + agg@Wn1 + b1), operands all from LDS ----
    frag_cd acc[4];
#pragma unroll
    for (int ft = 0; ft < 4; ++ft) acc[ft] = (frag_cd)(0.f);

    const int xrow = nodeq * 16 + l15;
    const int xswz = (xrow & 7) << 4;
#pragma unroll
    for (int kb = 0; kb < 4; ++kb) {
      int base = kb * 64 + q * 16;
      frag_ab axk = *(const frag_ab*)(cur + xrow * 256 + (base ^ xswz));
      frag_ab agk = *(const frag_ab*)(cur + 16384 + xrow * 256 + (base ^ xswz));
      frag_ab fs[4], fn[4];
#pragma unroll
      for (int ft = 0; ft < 4; ++ft) {
        int wrow = fbase + ft * 16 + l15;
        int woff = base ^ ((wrow & 7) << 4);
        fs[ft] = *(const frag_ab*)(sL + wrow * 256 + woff);
        fn[ft] = *(const frag_ab*)(sL + 32768 + wrow * 256 + woff);
      }
#pragma unroll
      for (int ft = 0; ft < 4; ++ft) {
        acc[ft] = __builtin_amdgcn_mfma_f32_16x16x32_bf16(fs[ft], axk, acc[ft], 0, 0, 0);
        acc[ft] = __builtin_amdgcn_mfma_f32_16x16x32_bf16(fn[ft], agk, acc[ft], 0, 0, 0);
      }
    }

    lgkm_barrier();  // B2: all phase-1 x reads done before h1 overwrites (DMA stays in flight)

    // epilogue 1: relu(acc + b1) -> h1 (cur x region, same swizzle)
#pragma unroll
    for (int ft = 0; ft < 4; ++ft) {
      int f0 = fbase + ft * 16 + q * 4;
      ushort4 o;
      o.x = f2b(fmaxf(acc[ft][0] + bv1[ft].x, 0.f));
      o.y = f2b(fmaxf(acc[ft][1] + bv1[ft].y, 0.f));
      o.z = f2b(fmaxf(acc[ft][2] + bv1[ft].z, 0.f));
      o.w = f2b(fmaxf(acc[ft][3] + bv1[ft].w, 0.f));
      *(ushort4*)(cur + xrow * 256 + ((f0 * 2) ^ xswz)) = o;
    }

    lgkm_barrier();  // B3: h1 visible to all waves (DMA still in flight)

    // ---- phase 2: out = h1@Ws2 + b2 (fhalf 0), g = h1@Wn2 (fhalf 1) ----
    const char* w2b = sL + 65536 + fhalf * 16384;
    frag_cd acc2[4];
#pragma unroll
    for (int ft = 0; ft < 4; ++ft) acc2[ft] = (frag_cd)(0.f);

#pragma unroll
    for (int kb = 0; kb < 4; ++kb) {
      int base = kb * 64 + q * 16;
      frag_ab ah = *(const frag_ab*)(cur + xrow * 256 + (base ^ xswz));
      frag_ab w2[4];
#pragma unroll
      for (int ft = 0; ft < 4; ++ft) {
        int wr = ft * 16 + l15;
        w2[ft] = *(const frag_ab*)(w2b + wr * 256 + (base ^ ((wr & 7) << 4)));
      }
#pragma unroll
      for (int ft = 0; ft < 4; ++ft)
        acc2[ft] = __builtin_amdgcn_mfma_f32_16x16x32_bf16(w2[ft], ah, acc2[ft], 0, 0, 0);
    }

    int node = tt * 64 + nodeq * 16 + l15;
    if (node < N) {
      if (fhalf == 0) {
#pragma unroll
        for (int ft = 0; ft < 4; ++ft) {
          int f0 = ft * 16 + q * 4;
          float4 o;
          o.x = acc2[ft][0] + bv2[ft].x;
          o.y = acc2[ft][1] + bv2[ft].y;
          o.z = acc2[ft][2] + bv2[ft].z;
          o.w = acc2[ft][3] + bv2[ft].w;
          *(float4*)(out + (size_t)node * M2 + f0) = o;
        }
      } else {
#pragma unroll
        for (int ft = 0; ft < 4; ++ft) {
          int f0 = ft * 16 + q * 4;
          ushort4 o;
          o.x = f2b(acc2[ft][0]);
          o.y = f2b(acc2[ft][1]);
          o.z = f2b(acc2[ft][2]);
          o.w = f2b(acc2[ft][3]);
          *(ushort4*)(g + (size_t)node * M2 + f0) = o;
        }
      }
    }
  }
}

extern "C" void kernel_launch(void* const* d_in, const int* in_sizes, int n_in,
                              void* d_out, int out_size, void* d_ws, size_t ws_size,
                              hipStream_t stream) {
  const float* x   = (const float*)d_in[0];
  const int*   src = (const int*)d_in[1];
  const int*   dst = (const int*)d_in[2];
  const float* Ws1 = (const float*)d_in[3];
  const float* Wn1 = (const float*)d_in[4];
  const float* b1  = (const float*)d_in[5];
  const float* Ws2 = (const float*)d_in[6];
  const float* Wn2 = (const float*)d_in[7];
  const float* b2  = (const float*)d_in[8];
  float* out = (float*)d_out;

  char* ws = (char*)d_ws;
  size_t off = 0;
  auto alloc = [&](size_t bytes) {
    void* p = ws + off;
    off = (off + bytes + 4095) & ~(size_t)4095;
    return p;
  };
  int* gbucket  = (int*)alloc((size_t)NBKT * 4);
  int* ebuf     = (int*)alloc((size_t)NBKT * BSTRIDE * 4);      // 3.28 MB, packed src|ln<<20
  int* rp       = (int*)alloc((size_t)NBKT * 126 * 4);          // padded row_ptr (126/bucket)
  int* csr_src  = (int*)alloc((size_t)NBKT * BSTRIDE * 4);      // padded node-sorted src
  unsigned short* xb   = (unsigned short*)alloc((size_t)N_NODES * K_DIM * 2);
  unsigned short* aggb = (unsigned short*)alloc((size_t)N_NODES * K_DIM * 2);
  unsigned short* g    = (unsigned short*)alloc((size_t)N_NODES * M2 * 2);
  unsigned short* Ws1T = (unsigned short*)alloc((size_t)128 * 128 * 2);
  unsigned short* Wn1T = (unsigned short*)alloc((size_t)128 * 128 * 2);
  unsigned short* Ws2T = (unsigned short*)alloc((size_t)64 * 128 * 2);
  unsigned short* Wn2T = (unsigned short*)alloc((size_t)64 * 128 * 2);

  hipMemsetAsync(gbucket, 0, (size_t)NBKT * 4, stream);

  // fused: single-pass bucket build (hist->reserve->scatter) + x->bf16 + weight transposes
  conv_all<<<HIST_BLOCKS + XB_BLOCKS + WB_BLOCKS, 256, 0, stream>>>(
      x, xb, Ws1, Wn1, Ws2, Wn2, Ws1T, Wn1T, Ws2T, Wn2T, src, dst, gbucket, ebuf);

  // fused per-bucket CSR sort + layer-1 gather-mean (emits rp/csr_src for agg2)
  bucket_csr_agg1<<<NBKT, 512, 0, stream>>>(xb, ebuf, gbucket, rp, csr_src, aggb);

  // fused layer-1 + layer-2 GEMMs: persistent blocks, weights staged once, tile-ahead DMA
  sage_fused_gemm<<<GEMM_GRID, 512, 0, stream>>>(
      xb, aggb, Ws1T, Wn1T, b1, Ws2T, Wn2T, b2, out, g, N_NODES);

  // layer-2 aggregation (adds mean(g) into out)
  {
    long t = (long)N_NODES * 8;
    aggregate64_add<<<(int)((t + 255) / 256), 256, 0, stream>>>(g, rp, csr_src, out, N_NODES);
  }
}

// Round 13
// 203.207 us; speedup vs baseline: 1.0484x; 1.0484x over previous
//
#include <hip/hip_runtime.h>

#define N_NODES 100000
#define N_EDGES 600000
#define K_DIM 128
#define M2 64
#define NT_TILES ((N_NODES + 63) / 64)        // 1563 64-node tiles
#define GEMM_GRID 256

// bucket build
#define NBKT 800                              // buckets
#define NPB 125                               // nodes per bucket (800*125 = 100000)
#define HIST_BLOCKS 64
#define EPB (N_EDGES / HIST_BLOCKS)           // 9375 edges per hist block (exact)
#define BSTRIDE 1024                          // fixed per-bucket capacity; Binomial max ~890 (>10 sigma)

using frag_ab = __attribute__((ext_vector_type(8))) short;   // 8 bf16 = 4 VGPRs
using frag_cd = __attribute__((ext_vector_type(4))) float;   // 4 fp32 acc

// fp32 -> bf16 round-to-nearest-even
__device__ __forceinline__ unsigned short f2b(float f) {
  unsigned u = __builtin_bit_cast(unsigned, f);
  u = (u + 0x7fffu + ((u >> 16) & 1u)) >> 16;
  return (unsigned short)u;
}

// async global->LDS, 16 B per lane. LDS dest wave-uniform (HW adds lane*16);
// global src per-lane (swizzled LDS layouts = pre-swizzle the source).
__device__ __forceinline__ void gload_lds16(const void* gsrc, void* ldst) {
  __builtin_amdgcn_global_load_lds(
      (const __attribute__((address_space(1))) void*)gsrc,
      (__attribute__((address_space(3))) void*)ldst, 16, 0, 0);
}

// raw barrier: drain LDS ops only, keep DMA/stores (vmcnt) in flight
__device__ __forceinline__ void lgkm_barrier() {
  __builtin_amdgcn_sched_barrier(0);
  asm volatile("s_waitcnt lgkmcnt(0)" ::: "memory");
  __builtin_amdgcn_s_barrier();
  __builtin_amdgcn_sched_barrier(0);
}

// ---------------- fused: bucket-hist(+pos) + x->bf16 (widened) + weight transposes ----------------
// v12: (a) xb section widened — 2 float4 loads -> 1 ushort8 store per thread (halves store
// instruction count, ILP=2, 6250 blocks). conv_all was 42-50us at 14% HBM across ALL rounds
// regardless of atomic scheme -> VMEM-issue/latency-bound, not atomic-bound.
// (b) scatter moved back to its own 2344-block kernel (v11's 64-block fused scatter was a
// ~8us 1-wave/CU random-store tail); hist captures pos[e] + reserves base_tbl, scatter is
// atomic-free; fixed-stride buckets keep the no-scan property (scan_buckets stays deleted).
// NOTE (v8): no edge-parallel LDS-f32-atomic aggregation (16-way ds_add conflict = 503us).
#define XB_BLOCKS ((N_NODES * K_DIM / 8 + 255) / 256)            // 6250 (2 float4 per thread)
#define W_ELEMS ((128 + 128 + 64 + 64) * 128)                    // 49152
#define WB_BLOCKS ((W_ELEMS + 255) / 256)                        // 192
__global__ __launch_bounds__(256) void conv_all(const float* __restrict__ x,
                                                unsigned short* __restrict__ xb,
                                                const float* __restrict__ Ws1,
                                                const float* __restrict__ Wn1,
                                                const float* __restrict__ Ws2,
                                                const float* __restrict__ Wn2,
                                                unsigned short* __restrict__ Ws1T,
                                                unsigned short* __restrict__ Wn1T,
                                                unsigned short* __restrict__ Ws2T,
                                                unsigned short* __restrict__ Wn2T,
                                                const int* __restrict__ dst,
                                                int* __restrict__ pos,
                                                int* __restrict__ gbucket,
                                                int* __restrict__ base_tbl) {
  __shared__ int lcnt[NBKT];
  if (blockIdx.x < HIST_BLOCKS) {
    int tid = threadIdx.x;
    for (int i = tid; i < NBKT; i += 256) lcnt[i] = 0;
    __syncthreads();
    int e0 = blockIdx.x * EPB;
    for (int e = e0 + tid; e < e0 + EPB; e += 256) {
      int b = dst[e] / NPB;
      pos[e] = atomicAdd(&lcnt[b], 1);     // LDS atomic with capture
    }
    __syncthreads();
    for (int i = tid; i < NBKT; i += 256) {
      int c = lcnt[i];
      if (c) base_tbl[blockIdx.x * NBKT + i] = atomicAdd(&gbucket[i], c);
    }
  } else if (blockIdx.x < HIST_BLOCKS + XB_BLOCKS) {
    long t = (long)(blockIdx.x - HIST_BLOCKS) * 256 + threadIdx.x;
    long i = t * 2;                          // float4 index; 2 consecutive per thread
    if (i >= (long)N_NODES * K_DIM / 4) return;
    float4 v0 = *(const float4*)(x + i * 4);
    float4 v1 = *(const float4*)(x + i * 4 + 4);
    ushort4 o0, o1;
    o0.x = f2b(v0.x); o0.y = f2b(v0.y); o0.z = f2b(v0.z); o0.w = f2b(v0.w);
    o1.x = f2b(v1.x); o1.y = f2b(v1.y); o1.z = f2b(v1.z); o1.w = f2b(v1.w);
    // one 16-B store (8 bf16)
    *(uint4*)(xb + i * 4) = uint4{
        (unsigned)o0.x | ((unsigned)o0.y << 16),
        (unsigned)o0.z | ((unsigned)o0.w << 16),
        (unsigned)o1.x | ((unsigned)o1.y << 16),
        (unsigned)o1.z | ((unsigned)o1.w << 16)};
  } else {
    int i = (blockIdx.x - HIST_BLOCKS - XB_BLOCKS) * 256 + threadIdx.x;
    if (i >= W_ELEMS) return;
    const float* W;
    unsigned short* WT;
    int M, li;
    if (i < 128 * 128)               { W = Ws1; WT = Ws1T; M = 128; li = i; }
    else if (i < 2 * 128 * 128)      { W = Wn1; WT = Wn1T; M = 128; li = i - 128 * 128; }
    else if (i < 2 * 128 * 128 + 64 * 128) { W = Ws2; WT = Ws2T; M = 64; li = i - 2 * 128 * 128; }
    else                             { W = Wn2; WT = Wn2T; M = 64; li = i - 2 * 128 * 128 - 64 * 128; }
    int n = li >> 7, k = li & 127;   // li = n*128 + k
    WT[li] = f2b(W[k * M + n]);
  }
}

// ---------------- scatter edges into fixed-stride buckets (atomic-free, 2344 blocks) ----------------
__global__ __launch_bounds__(256) void bucket_scatter(const int* __restrict__ src,
                                                      const int* __restrict__ dst,
                                                      const int* __restrict__ pos,
                                                      const int* __restrict__ base_tbl,
                                                      int* __restrict__ ebuf) {
  int e = blockIdx.x * 256 + threadIdx.x;
  if (e >= N_EDGES) return;
  int d = dst[e];
  int b = d / NPB;
  int p = base_tbl[(e / EPB) * NBKT + b] + pos[e];
  ebuf[b * BSTRIDE + p] = src[e] | ((d - b * NPB) << 20);
}

// ---------------- fused per-bucket CSR sort + layer-1 gather-mean ----------------
// bs = b*BSTRIDE (fixed stride; no scan). Emits padded rp[b*126+i] + csr_src for
// aggregate64_add. Gather stays NODE-parallel with register accumulators (v8 lesson).
__global__ __launch_bounds__(512) void bucket_csr_agg1(const unsigned short* __restrict__ xb,
                                                       const int* __restrict__ ebuf,
                                                       const int* __restrict__ gbucket,
                                                       int* __restrict__ rp,
                                                       int* __restrict__ csr_src,
                                                       unsigned short* __restrict__ aggb) {
  __shared__ int cnt[128];
  __shared__ int sedge[BSTRIDE];   // node-sorted src ids, 4 KB
  int tid = threadIdx.x, b = blockIdx.x;
  int bs = b * BSTRIDE;
  int ecnt = gbucket[b];
  for (int i = tid; i < 128; i += 512) cnt[i] = 0;
  __syncthreads();

  int ln[2], lp[2], sv[2];
#pragma unroll
  for (int j = 0; j < 2; ++j) {            // capacity 2*512 = 1024 = BSTRIDE
    int p = tid + j * 512;
    if (p < ecnt) {
      int pk = ebuf[bs + p];
      sv[j] = pk & 0xFFFFF;
      ln[j] = pk >> 20;
      lp[j] = atomicAdd(&cnt[ln[j]], 1);
    }
  }
  __syncthreads();
  // inclusive scan over cnt[0..127]
  for (int off = 1; off < 128; off <<= 1) {
    int t = 0;
    if (tid < 128 && tid >= off) t = cnt[tid - off];
    __syncthreads();
    if (tid < 128) cnt[tid] += t;
    __syncthreads();
  }
  for (int i = tid; i < 126; i += 512)
    rp[b * 126 + i] = bs + (i ? cnt[i - 1] : 0);   // i=125 -> cnt[124] = bucket total
#pragma unroll
  for (int j = 0; j < 2; ++j) {
    int p = tid + j * 512;
    if (p < ecnt) {
      int l = ln[j];
      int loc = (l ? cnt[l - 1] : 0) + lp[j];
      sedge[loc] = sv[j];
      csr_src[bs + loc] = sv[j];   // for aggregate64_add
    }
  }
  __syncthreads();

  // gather-mean from LDS edge list: 16 threads/node, 32 nodes per pass
  int nl = tid >> 4;
  int c = (tid & 15) << 3;   // 8 bf16 per thread
  for (int n0 = 0; n0 < NPB; n0 += 32) {
    int node = n0 + nl;
    if (node < NPB) {
      int beg = node ? cnt[node - 1] : 0;
      int end = cnt[node];
      float acc[8];
#pragma unroll
      for (int j = 0; j < 8; ++j) acc[j] = 0.f;
      for (int e0 = beg; e0 < end; e0 += 8) {
        int idx[8];
#pragma unroll
        for (int p = 0; p < 8; ++p) idx[p] = sedge[min(e0 + p, end - 1)];
        uint4 v[8];
#pragma unroll
        for (int p = 0; p < 8; ++p) v[p] = *(const uint4*)(xb + (size_t)idx[p] * K_DIM + c);
#pragma unroll
        for (int p = 0; p < 8; ++p) {
          float m = (e0 + p < end) ? 1.f : 0.f;
          unsigned u[4] = {v[p].x, v[p].y, v[p].z, v[p].w};
#pragma unroll
          for (int j = 0; j < 4; ++j) {
            acc[2 * j]     += m * __builtin_bit_cast(float, u[j] << 16);
            acc[2 * j + 1] += m * __builtin_bit_cast(float, u[j] & 0xffff0000u);
          }
        }
      }
      float inv = 1.0f / (float)max(end - beg, 1);
      uint4 o;
      unsigned* op = (unsigned*)&o;
#pragma unroll
      for (int j = 0; j < 4; ++j) {
        unsigned lo = f2b(acc[2 * j] * inv);
        unsigned hi = f2b(acc[2 * j + 1] * inv);
        op[j] = lo | (hi << 16);
      }
      *(uint4*)(aggb + (size_t)(b * NPB + node) * K_DIM + c) = o;
    }
  }
}

// ---------------- gather-mean-add, 64 bf16 cols -> out fp32 (padded rp indexing) ----------------
__global__ __launch_bounds__(256) void aggregate64_add(const unsigned short* __restrict__ g,
                                                       const int* __restrict__ rp,
                                                       const int* __restrict__ csr_src,
                                                       float* __restrict__ out, int n) {
  int t = blockIdx.x * blockDim.x + threadIdx.x;
  int node = t >> 3;
  int c = (t & 7) << 3;  // 8 bf16 per thread
  if (node >= n) return;
  int b = node / NPB;
  int i = node - b * NPB;
  int beg = rp[b * 126 + i], end = rp[b * 126 + i + 1];
  float acc[8];
#pragma unroll
  for (int j = 0; j < 8; ++j) acc[j] = 0.f;

  if (end > beg) {
    for (int e0 = beg; e0 < end; e0 += 8) {
      int idx[8];
#pragma unroll
      for (int p = 0; p < 8; ++p) idx[p] = csr_src[min(e0 + p, end - 1)];
      uint4 v[8];
#pragma unroll
      for (int p = 0; p < 8; ++p) v[p] = *(const uint4*)(g + (size_t)idx[p] * M2 + c);
#pragma unroll
      for (int p = 0; p < 8; ++p) {
        float m = (e0 + p < end) ? 1.f : 0.f;
        unsigned u[4] = {v[p].x, v[p].y, v[p].z, v[p].w};
#pragma unroll
        for (int j = 0; j < 4; ++j) {
          acc[2 * j]     += m * __builtin_bit_cast(float, u[j] << 16);
          acc[2 * j + 1] += m * __builtin_bit_cast(float, u[j] & 0xffff0000u);
        }
      }
    }
  }
  float inv = 1.0f / (float)max(end - beg, 1);
  float* op = out + (size_t)node * M2 + c;
  float4 o0 = *(float4*)(op);
  float4 o1 = *(float4*)(op + 4);
  o0.x += acc[0] * inv; o0.y += acc[1] * inv; o0.z += acc[2] * inv; o0.w += acc[3] * inv;
  o1.x += acc[4] * inv; o1.y += acc[5] * inv; o1.z += acc[6] * inv; o1.w += acc[7] * inv;
  *(float4*)(op) = o0;
  *(float4*)(op + 4) = o1;
}

// stage one 64-node tile of x+agg (32 KB) into LDS dbuf half, swizzled source
__device__ __forceinline__ void stage_tile(const unsigned short* xb, const unsigned short* aggb,
                                           int t, char* dstbase, int tid, int wave, int N) {
#pragma unroll
  for (int it = 0; it < 2; ++it) {
    int L = it * 8192 + tid * 16;            // [0, 16384)
    int row = L >> 8;                        // 0..63
    int srb = (L & 255) ^ ((row & 7) << 4);  // inverse-swizzled source byte
    int node = t * 64 + row;
    if (node >= N) node = N - 1;             // clamp (garbage rows never stored)
    char* d = dstbase + it * 8192 + wave * 1024;  // wave-uniform; HW adds lane*16
    gload_lds16((const char*)xb + (size_t)node * 256 + srb, d);
    gload_lds16((const char*)aggb + (size_t)node * 256 + srb, d + 16384);
  }
}

// ---------------- fused both-layer GEMM (v5: persistent, everything via DMA+LDS) ----------------
// Confirmed working (rounds 6-12). Rule from v1-v4: any global->VGPR operand load feeding
// MFMA gets latency-serialized by the compiler; global_load_lds is the only reliably-batched
// path. Persistent blocks (grid=256, 1/CU, 512 thr), weights staged ONCE, x/agg 2x32K dbuf
// with one-tile-ahead DMA; raw lgkm-only barriers keep the prefetch DMA in flight.
__global__ __launch_bounds__(512, 2) void sage_fused_gemm(const unsigned short* __restrict__ xb,
                                                          const unsigned short* __restrict__ aggb,
                                                          const unsigned short* __restrict__ Ws1T,
                                                          const unsigned short* __restrict__ Wn1T,
                                                          const float* __restrict__ b1,
                                                          const unsigned short* __restrict__ Ws2T,
                                                          const unsigned short* __restrict__ Wn2T,
                                                          const float* __restrict__ b2,
                                                          float* __restrict__ out,
                                                          unsigned short* __restrict__ g, int N) {
  // [0,32K) Ws1T | [32K,64K) Wn1T | [64K,80K) Ws2T | [80K,96K) Wn2T | [96K,128K) buf0 | [128K,160K) buf1
  __shared__ char sL[163840];

  const int tid = threadIdx.x;
  const int wave = tid >> 6;
  const int lane = tid & 63;
  const int l15 = lane & 15;
  const int q = lane >> 4;
  const int nodeq = wave >> 1;     // 0..3 -> 16-node strip
  const int fhalf = wave & 1;      // phase-1 feat half / phase-2 output matrix
  const int fbase = fhalf * 64;

  // ---- prologue: stage all weights (96 KB) + first tile (once per block) ----
#pragma unroll
  for (int it = 0; it < 4; ++it) {           // W1: 2 x 32K
    int L = it * 8192 + tid * 16;
    int row = L >> 8;
    int srb = (L & 255) ^ ((row & 7) << 4);
    char* d = sL + it * 8192 + wave * 1024;
    gload_lds16((const char*)Ws1T + row * 256 + srb, d);
    gload_lds16((const char*)Wn1T + row * 256 + srb, d + 32768);
  }
#pragma unroll
  for (int it = 0; it < 2; ++it) {           // W2: 2 x 16K
    int L = it * 8192 + tid * 16;
    int row = L >> 8;
    int srb = (L & 255) ^ ((row & 7) << 4);
    char* d = sL + 65536 + it * 8192 + wave * 1024;
    gload_lds16((const char*)Ws2T + row * 256 + srb, d);
    gload_lds16((const char*)Wn2T + row * 256 + srb, d + 16384);
  }
  int tt = blockIdx.x;
  if (tt < NT_TILES) stage_tile(xb, aggb, tt, sL + 98304, tid, wave, N);

  // ---- biases: loop-invariant plain loads (hoisted; once per block) ----
  float4 bv1[4], bv2[4];
#pragma unroll
  for (int ft = 0; ft < 4; ++ft) {
    bv1[ft] = *(const float4*)(b1 + fbase + ft * 16 + q * 4);
    bv2[ft] = *(const float4*)(b2 + ft * 16 + q * 4);
  }

  // ---- persistent tile loop ----
  int li = 0;
  for (; tt < NT_TILES; tt += GEMM_GRID, ++li) {
    char* cur = sL + 98304 + (li & 1) * 32768;
    char* nxt = sL + 98304 + ((li + 1) & 1) * 32768;

    __syncthreads();  // B1: vmcnt(0) drain -> DMA(cur) complete; prev phase-2 LDS reads done

    if (tt + GEMM_GRID < NT_TILES)           // prefetch next tile (stays in flight across
      stage_tile(xb, aggb, tt + GEMM_GRID, nxt, tid, wave, N);  // the raw barriers below)

    // ---- phase 1: h1 = relu(x@Ws1 + agg@Wn1 + b1), operands all from LDS ----
    frag_cd acc[4];
#pragma unroll
    for (int ft = 0; ft < 4; ++ft) acc[ft] = (frag_cd)(0.f);

    const int xrow = nodeq * 16 + l15;
    const int xswz = (xrow & 7) << 4;
#pragma unroll
    for (int kb = 0; kb < 4; ++kb) {
      int base = kb * 64 + q * 16;
      frag_ab axk = *(const frag_ab*)(cur + xrow * 256 + (base ^ xswz));
      frag_ab agk = *(const frag_ab*)(cur + 16384 + xrow * 256 + (base ^ xswz));
      frag_ab fs[4], fn[4];
#pragma unroll
      for (int ft = 0; ft < 4; ++ft) {
        int wrow = fbase + ft * 16 + l15;
        int woff = base ^ ((wrow & 7) << 4);
        fs[ft] = *(const frag_ab*)(sL + wrow * 256 + woff);
        fn[ft] = *(const frag_ab*)(sL + 32768 + wrow * 256 + woff);
      }
#pragma unroll
      for (int ft = 0; ft < 4; ++ft) {
        acc[ft] = __builtin_amdgcn_mfma_f32_16x16x32_bf16(fs[ft], axk, acc[ft], 0, 0, 0);
        acc[ft] = __builtin_amdgcn_mfma_f32_16x16x32_bf16(fn[ft], agk, acc[ft], 0, 0, 0);
      }
    }

    lgkm_barrier();  // B2: all phase-1 x reads done before h1 overwrites (DMA stays in flight)

    // epilogue 1: relu(acc + b1) -> h1 (cur x region, same swizzle)
#pragma unroll
    for (int ft = 0; ft < 4; ++ft) {
      int f0 = fbase + ft * 16 + q * 4;
      ushort4 o;
      o.x = f2b(fmaxf(acc[ft][0] + bv1[ft].x, 0.f));
      o.y = f2b(fmaxf(acc[ft][1] + bv1[ft].y, 0.f));
      o.z = f2b(fmaxf(acc[ft][2] + bv1[ft].z, 0.f));
      o.w = f2b(fmaxf(acc[ft][3] + bv1[ft].w, 0.f));
      *(ushort4*)(cur + xrow * 256 + ((f0 * 2) ^ xswz)) = o;
    }

    lgkm_barrier();  // B3: h1 visible to all waves (DMA still in flight)

    // ---- phase 2: out = h1@Ws2 + b2 (fhalf 0), g = h1@Wn2 (fhalf 1) ----
    const char* w2b = sL + 65536 + fhalf * 16384;
    frag_cd acc2[4];
#pragma unroll
    for (int ft = 0; ft < 4; ++ft) acc2[ft] = (frag_cd)(0.f);

#pragma unroll
    for (int kb = 0; kb < 4; ++kb) {
      int base = kb * 64 + q * 16;
      frag_ab ah = *(const frag_ab*)(cur + xrow * 256 + (base ^ xswz));
      frag_ab w2[4];
#pragma unroll
      for (int ft = 0; ft < 4; ++ft) {
        int wr = ft * 16 + l15;
        w2[ft] = *(const frag_ab*)(w2b + wr * 256 + (base ^ ((wr & 7) << 4)));
      }
#pragma unroll
      for (int ft = 0; ft < 4; ++ft)
        acc2[ft] = __builtin_amdgcn_mfma_f32_16x16x32_bf16(w2[ft], ah, acc2[ft], 0, 0, 0);
    }

    int node = tt * 64 + nodeq * 16 + l15;
    if (node < N) {
      if (fhalf == 0) {
#pragma unroll
        for (int ft = 0; ft < 4; ++ft) {
          int f0 = ft * 16 + q * 4;
          float4 o;
          o.x = acc2[ft][0] + bv2[ft].x;
          o.y = acc2[ft][1] + bv2[ft].y;
          o.z = acc2[ft][2] + bv2[ft].z;
          o.w = acc2[ft][3] + bv2[ft].w;
          *(float4*)(out + (size_t)node * M2 + f0) = o;
        }
      } else {
#pragma unroll
        for (int ft = 0; ft < 4; ++ft) {
          int f0 = ft * 16 + q * 4;
          ushort4 o;
          o.x = f2b(acc2[ft][0]);
          o.y = f2b(acc2[ft][1]);
          o.z = f2b(acc2[ft][2]);
          o.w = f2b(acc2[ft][3]);
          *(ushort4*)(g + (size_t)node * M2 + f0) = o;
        }
      }
    }
  }
}

extern "C" void kernel_launch(void* const* d_in, const int* in_sizes, int n_in,
                              void* d_out, int out_size, void* d_ws, size_t ws_size,
                              hipStream_t stream) {
  const float* x   = (const float*)d_in[0];
  const int*   src = (const int*)d_in[1];
  const int*   dst = (const int*)d_in[2];
  const float* Ws1 = (const float*)d_in[3];
  const float* Wn1 = (const float*)d_in[4];
  const float* b1  = (const float*)d_in[5];
  const float* Ws2 = (const float*)d_in[6];
  const float* Wn2 = (const float*)d_in[7];
  const float* b2  = (const float*)d_in[8];
  float* out = (float*)d_out;

  char* ws = (char*)d_ws;
  size_t off = 0;
  auto alloc = [&](size_t bytes) {
    void* p = ws + off;
    off = (off + bytes + 4095) & ~(size_t)4095;
    return p;
  };
  int* pos      = (int*)alloc((size_t)N_EDGES * 4);
  int* gbucket  = (int*)alloc((size_t)NBKT * 4);
  int* base_tbl = (int*)alloc((size_t)HIST_BLOCKS * NBKT * 4);
  int* ebuf     = (int*)alloc((size_t)NBKT * BSTRIDE * 4);      // 3.28 MB, packed src|ln<<20
  int* rp       = (int*)alloc((size_t)NBKT * 126 * 4);          // padded row_ptr (126/bucket)
  int* csr_src  = (int*)alloc((size_t)NBKT * BSTRIDE * 4);      // padded node-sorted src
  unsigned short* xb   = (unsigned short*)alloc((size_t)N_NODES * K_DIM * 2);
  unsigned short* aggb = (unsigned short*)alloc((size_t)N_NODES * K_DIM * 2);
  unsigned short* g    = (unsigned short*)alloc((size_t)N_NODES * M2 * 2);
  unsigned short* Ws1T = (unsigned short*)alloc((size_t)128 * 128 * 2);
  unsigned short* Wn1T = (unsigned short*)alloc((size_t)128 * 128 * 2);
  unsigned short* Ws2T = (unsigned short*)alloc((size_t)64 * 128 * 2);
  unsigned short* Wn2T = (unsigned short*)alloc((size_t)64 * 128 * 2);

  hipMemsetAsync(gbucket, 0, (size_t)NBKT * 4, stream);

  // fused: bucket hist(+pos) + x->bf16 (2xfloat4 -> ushort8) + weight transposes
  conv_all<<<HIST_BLOCKS + XB_BLOCKS + WB_BLOCKS, 256, 0, stream>>>(
      x, xb, Ws1, Wn1, Ws2, Wn2, Ws1T, Wn1T, Ws2T, Wn2T, dst, pos, gbucket, base_tbl);

  // atomic-free scatter into fixed-stride buckets (2344 blocks hide random-store latency)
  bucket_scatter<<<(N_EDGES + 255) / 256, 256, 0, stream>>>(
      src, dst, pos, base_tbl, ebuf);

  // fused per-bucket CSR sort + layer-1 gather-mean (emits rp/csr_src for agg2)
  bucket_csr_agg1<<<NBKT, 512, 0, stream>>>(xb, ebuf, gbucket, rp, csr_src, aggb);

  // fused layer-1 + layer-2 GEMMs: persistent blocks, weights staged once, tile-ahead DMA
  sage_fused_gemm<<<GEMM_GRID, 512, 0, stream>>>(
      xb, aggb, Ws1T, Wn1T, b1, Ws2T, Wn2T, b2, out, g, N_NODES);

  // layer-2 aggregation (adds mean(g) into out)
  {
    long t = (long)N_NODES * 8;
    aggregate64_add<<<(int)((t + 255) / 256), 256, 0, stream>>>(g, rp, csr_src, out, N_NODES);
  }
}